// Round 12
// baseline (268.608 us; speedup 1.0000x reference)
//
#include <hip/hip_runtime.h>

#define NB 8
#define NNODE 10000
#define NEDGE 160000
#define MROWS 80000
#define TIN 12
#define EPSBN 1e-5f

typedef __attribute__((ext_vector_type(8))) short bf16x8;
typedef __attribute__((ext_vector_type(4))) float f32x4;
typedef unsigned short u16;
typedef unsigned int u32;

static __device__ __forceinline__ u16 f2bf(float f) {
    unsigned int u = __builtin_bit_cast(unsigned int, f);
    u = (u + 0x7fffu + ((u >> 16) & 1u)) >> 16;
    return (u16)u;
}
static __device__ __forceinline__ float bf2f(u16 h) {
    unsigned int u = ((unsigned int)h) << 16;
    return __builtin_bit_cast(float, u);
}

// ---------------------------------------------------------------------------
// fused pre-stage: [0,313) transpose_x | [313,938) deg | [938,1066) prep
__global__ __launch_bounds__(256) void fused_pre(const float* __restrict__ x,
                                                 u16* __restrict__ X0,
                                                 const int* __restrict__ ei,
                                                 int* __restrict__ degi,
                                                 const float* __restrict__ Wl0,
                                                 const float* __restrict__ Wr0,
                                                 const float* __restrict__ bl0,
                                                 const float* __restrict__ Wl12,
                                                 const float* __restrict__ Wr12,
                                                 const float* __restrict__ bl12,
                                                 const float* __restrict__ g,
                                                 const float* __restrict__ bb,
                                                 const float* __restrict__ m,
                                                 const float* __restrict__ v,
                                                 const float* __restrict__ hW,
                                                 u16* __restrict__ W0T, u16* __restrict__ W1T,
                                                 u16* __restrict__ W2T, u16* __restrict__ W3T,
                                                 float* __restrict__ bias012) {
    int blk = blockIdx.x;
    if (blk < 313) {
        int row = blk * 256 + threadIdx.x;        // row = n*8 + b
        if (row >= MROWS) return;
        int n = row >> 3, b = row & 7;
        u32 w[12];
        #pragma unroll
        for (int tt = 0; tt < 12; ++tt) {
            float2 vv = *(const float2*)&x[(size_t)((b * 12 + tt) * NNODE + n) * 2];
            w[tt] = (u32)f2bf(vv.x) | ((u32)f2bf(vv.y) << 16);
        }
        u32* dst = (u32*)&X0[(size_t)row * 48 + 24];
        *(uint4*)(dst + 0) = make_uint4(w[0], w[1], w[2], w[3]);
        *(uint4*)(dst + 4) = make_uint4(w[4], w[5], w[6], w[7]);
        *(uint4*)(dst + 8) = make_uint4(w[8], w[9], w[10], w[11]);
    } else if (blk < 938) {
        int e = (blk - 313) * 256 + threadIdx.x;
        if (e < NEDGE) atomicAdd(&degi[ei[NEDGE + e]], 1);
    } else {
        int c = blk - 938, k = threadIdx.x;
        float s0 = g[c] / sqrtf(v[c] + EPSBN);
        float s1 = g[128 + c] / sqrtf(v[128 + c] + EPSBN);
        float s2 = g[256 + c] / sqrtf(v[256 + c] + EPSBN);
        if (k < 64) {
            float val = (k < 24) ? Wl0[k * 128 + c] : ((k < 48) ? Wr0[(k - 24) * 128 + c] : 0.0f);
            W0T[c * 64 + k] = f2bf(val * s0);
        }
        float v1 = (k < 128) ? Wl12[k * 128 + c] : Wr12[(k - 128) * 128 + c];
        W1T[c * 256 + k] = f2bf(v1 * s1);
        float v2 = (k < 128) ? Wl12[128 * 128 + k * 128 + c]
                             : Wr12[128 * 128 + (k - 128) * 128 + c];
        W2T[c * 256 + k] = f2bf(v2 * s2);
        if (k < 128 && c < 64) {
            // head weights, hi/lo bf16 split: rows 0..31 hi, 32..63 lo
            int cc = c & 31;
            float w3 = (cc < 24) ? hW[k * 24 + cc] : 0.0f;
            u16 hi = f2bf(w3);
            if (c < 32) W3T[c * 128 + k] = hi;
            else        W3T[c * 128 + k] = f2bf(w3 - bf2f(hi));
        }
        if (k < 3) {
            float sl = g[k * 128 + c] / sqrtf(v[k * 128 + c] + EPSBN);
            float blv = (k == 0) ? bl0[c] : bl12[(k - 1) * 128 + c];
            bias012[k * 128 + c] = blv * sl + bb[k * 128 + c] - m[k * 128 + c] * sl;
        }
    }
}

// prefix scan over deg -> row_ptr, inv_deg; also zeroes cursor
__global__ __launch_bounds__(1024) void scan_kernel(const int* __restrict__ degi,
                                                    int* __restrict__ row_ptr,
                                                    float* __restrict__ inv_deg,
                                                    int* __restrict__ cursor) {
    __shared__ int sdata[1024];
    const int t = threadIdx.x;
    const int CH = 10;
    const int i0 = t * CH;
    int sum = 0;
    for (int i = i0; i < i0 + CH && i < NNODE; ++i) sum += degi[i];
    sdata[t] = sum;
    for (int off = 1; off < 1024; off <<= 1) {
        __syncthreads();
        int vv = (t >= off) ? sdata[t - off] : 0;
        __syncthreads();
        sdata[t] += vv;
    }
    __syncthreads();
    int run = sdata[t] - sum;
    for (int i = i0; i < i0 + CH && i < NNODE; ++i) {
        row_ptr[i] = run;
        int d = degi[i];
        run += d;
        inv_deg[i] = 1.0f / (float)max(d, 1);
        cursor[i] = 0;
    }
    if (t == 1023) row_ptr[NNODE] = sdata[1023];
}

__global__ void csr_fill(const int* __restrict__ ei, const int* __restrict__ row_ptr,
                         int* __restrict__ cursor, int* __restrict__ csr_src) {
    int e = blockIdx.x * blockDim.x + threadIdx.x;
    if (e < NEDGE) {
        int d = ei[NEDGE + e];
        int pos = atomicAdd(&cursor[d], 1);
        csr_src[row_ptr[d] + pos] = ei[e];
    }
}

// mean-aggregation K=24 on row-major X0 (stride 48), 2 nodes/block, unroll-4
__global__ __launch_bounds__(192) void agg24(u16* __restrict__ X0,
                                             const int* __restrict__ rp,
                                             const int* __restrict__ cs,
                                             const float* __restrict__ inv) {
    int u = threadIdx.x;
    int n = blockIdx.x * 2 + (u / 96);
    int w = u % 96;
    int b = w / 12, cp = w % 12;
    int p0 = rp[n], p1 = rp[n + 1];
    float a0 = 0, a1 = 0, b0 = 0, b1 = 0, c0 = 0, c1 = 0, d0 = 0, d1 = 0;
    int p = p0;
    for (; p + 4 <= p1; p += 4) {
        int s0 = cs[p], s1 = cs[p + 1], s2 = cs[p + 2], s3 = cs[p + 3];
        u32 v0 = *(const u32*)&X0[(s0 * NB + b) * 48 + 24 + cp * 2];
        u32 v1 = *(const u32*)&X0[(s1 * NB + b) * 48 + 24 + cp * 2];
        u32 v2 = *(const u32*)&X0[(s2 * NB + b) * 48 + 24 + cp * 2];
        u32 v3 = *(const u32*)&X0[(s3 * NB + b) * 48 + 24 + cp * 2];
        a0 += bf2f((u16)(v0 & 0xffff)); a1 += bf2f((u16)(v0 >> 16));
        b0 += bf2f((u16)(v1 & 0xffff)); b1 += bf2f((u16)(v1 >> 16));
        c0 += bf2f((u16)(v2 & 0xffff)); c1 += bf2f((u16)(v2 >> 16));
        d0 += bf2f((u16)(v3 & 0xffff)); d1 += bf2f((u16)(v3 >> 16));
    }
    for (; p < p1; ++p) {
        int s = cs[p];
        u32 vv = *(const u32*)&X0[(s * NB + b) * 48 + 24 + cp * 2];
        a0 += bf2f((u16)(vv & 0xffff)); a1 += bf2f((u16)(vv >> 16));
    }
    float sc = inv[n];
    float r0 = (a0 + b0) + (c0 + d0), r1 = (a1 + b1) + (c1 + d1);
    u32 o = (u32)f2bf(r0 * sc) | ((u32)f2bf(r1 * sc) << 16);
    *(u32*)&X0[(n * NB + b) * 48 + cp * 2] = o;
}

// chunked mean-aggregation K=128: X layout [16 chunks][MROWS][16 cols],
// h in chunks 8..15, mean -> chunks 0..7. chunk = blockIdx&7 (XCD-pinned).
// 2 nodes/block (wave-per-node, 128 thr) -> 16 blocks/CU = 32 waves/CU
// (vs 64-thr blocks capped at 16 waves/CU by the WG/CU limit). unroll-4.
__global__ __launch_bounds__(128) void agg128c(u16* __restrict__ X,
                                               const int* __restrict__ rp,
                                               const int* __restrict__ cs,
                                               const float* __restrict__ inv) {
    int bid = blockIdx.x;
    int c = bid & 7;
    int n = (bid >> 3) * 2 + (threadIdx.x >> 6);   // wave w -> node 2*pair+w
    int l = threadIdx.x & 63;
    int b = l >> 3, q = l & 7;
    int p0 = rp[n], p1 = rp[n + 1];
    const u16* hb = X + ((size_t)(8 + c) * MROWS) * 16;
    float a0 = 0, a1 = 0, b0 = 0, b1 = 0, c0 = 0, c1 = 0, d0 = 0, d1 = 0;
    int p = p0;
    for (; p + 4 <= p1; p += 4) {
        int s0 = cs[p], s1 = cs[p + 1], s2 = cs[p + 2], s3 = cs[p + 3];
        u32 v0 = *(const u32*)&hb[(s0 * NB + b) * 16 + q * 2];
        u32 v1 = *(const u32*)&hb[(s1 * NB + b) * 16 + q * 2];
        u32 v2 = *(const u32*)&hb[(s2 * NB + b) * 16 + q * 2];
        u32 v3 = *(const u32*)&hb[(s3 * NB + b) * 16 + q * 2];
        a0 += bf2f((u16)(v0 & 0xffff)); a1 += bf2f((u16)(v0 >> 16));
        b0 += bf2f((u16)(v1 & 0xffff)); b1 += bf2f((u16)(v1 >> 16));
        c0 += bf2f((u16)(v2 & 0xffff)); c1 += bf2f((u16)(v2 >> 16));
        d0 += bf2f((u16)(v3 & 0xffff)); d1 += bf2f((u16)(v3 >> 16));
    }
    for (; p < p1; ++p) {
        int s = cs[p];
        u32 vv = *(const u32*)&hb[(s * NB + b) * 16 + q * 2];
        a0 += bf2f((u16)(vv & 0xffff)); a1 += bf2f((u16)(vv >> 16));
    }
    float sc = inv[n];
    float r0 = (a0 + b0) + (c0 + d0), r1 = (a1 + b1) + (c1 + d1);
    u32 o = (u32)f2bf(r0 * sc) | ((u32)f2bf(r1 * sc) << 16);
    *(u32*)&X[((size_t)c * MROWS + n * NB + b) * 16 + q * 2] = o;
}

// MFMA GEMM (r8 config, measured best): M-tile 320 x N 128, 10 waves, grid 250,
// W in LDS slab (conflict-free), A direct global->VGPR depth-1 prefetch.
// HEAD: fused MFMA 128->24 head.
#define LOADA(dst, stp) { \
    const int k0_ = (stp) * 32 + kg * 8; \
    _Pragma("unroll") \
    for (int m_ = 0; m_ < 4; ++m_) { \
        const int row_ = rowbase + m_ * 16; \
        const u16* ap_; \
        if (INC) ap_ = A + ((size_t)(k0_ >> 4) * MROWS + row_) * 16 + (k0_ & 15); \
        else     ap_ = A + (size_t)row_ * LDA + k0_; \
        dst[m_] = *(const bf16x8*)ap_; \
    } }

#define MFMAS(av, stp) { \
    const int k0_ = (stp) * 32 + kg * 8; \
    bf16x8 bv_[4]; \
    _Pragma("unroll") \
    for (int n_ = 0; n_ < 4; ++n_) \
        bv_[n_] = *(const bf16x8*)&BsF[(((k0_) >> 3) * 128 + (wc * 64 + n_ * 16 + r16)) * 8]; \
    _Pragma("unroll") \
    for (int m_ = 0; m_ < 4; ++m_) \
        _Pragma("unroll") \
        for (int n_ = 0; n_ < 4; ++n_) \
            acc[m_][n_] = __builtin_amdgcn_mfma_f32_16x16x32_bf16(av[m_], bv_[n_], acc[m_][n_], 0, 0, 0); }

template<int K, int LDA, bool INC, bool HEAD>
__global__ __launch_bounds__(640) void gemm_mfma(const u16* __restrict__ A,
                                                 const u16* __restrict__ WT,
                                                 const float* __restrict__ bias,
                                                 const u16* __restrict__ W3Tg,
                                                 const float* __restrict__ hb,
                                                 u16* __restrict__ outc,
                                                 float* __restrict__ outf) {
    constexpr int NSTEP = K / 32;
    constexpr int BS_BYTES = K * 128 * 2;                  // slab [K/8][128][8]
    constexpr int HS_BYTES = 320 * 134 * 2;                // 85760
    constexpr int W3_BYTES = 64 * 136 * 2;                 // 17408
    constexpr int HEAD_BYTES = HS_BYTES + W3_BYTES;        // 103168 >= BS_BYTES
    constexpr int SMEM_BYTES = HEAD ? (BS_BYTES > HEAD_BYTES ? BS_BYTES : HEAD_BYTES)
                                    : BS_BYTES;
    __shared__ __align__(16) char smem[SMEM_BYTES];
    short* BsF = (short*)smem;

    const int t = threadIdx.x;
    const int row0 = blockIdx.x * 320;
    const int lane = t & 63, wid = t >> 6;
    const int wr = wid >> 1, wc = wid & 1;
    const int r16 = lane & 15, kg = lane >> 4;

    if (t < 512) {
        const int col = t >> 2, q = t & 3;
        #pragma unroll
        for (int j = 0; j < K / 32; ++j) {
            int k0 = q * (K / 4) + j * 8;
            *(bf16x8*)&BsF[((k0 >> 3) * 128 + col) * 8] =
                *(const bf16x8*)&WT[col * K + k0];
        }
    }
    if (HEAD) {
        short* W3 = (short*)(smem + HS_BYTES);             // [64][136]
        for (int i = t; i < 1024; i += 640) {
            int row = i >> 4, j = i & 15;
            *(bf16x8*)&W3[row * 136 + j * 8] = *(const bf16x8*)&W3Tg[row * 128 + j * 8];
        }
    }
    __syncthreads();

    f32x4 acc[4][4];
    #pragma unroll
    for (int m = 0; m < 4; ++m)
        #pragma unroll
        for (int n = 0; n < 4; ++n)
            acc[m][n] = (f32x4){0.f, 0.f, 0.f, 0.f};

    const int rowbase = row0 + wr * 64 + r16;

    bf16x8 avA[4], avB[4];
    LOADA(avA, 0)
    #pragma unroll
    for (int s2 = 0; s2 < NSTEP; s2 += 2) {
        if (s2 + 1 < NSTEP) LOADA(avB, s2 + 1)
        MFMAS(avA, s2)
        if (s2 + 2 < NSTEP) LOADA(avA, s2 + 2)
        if (s2 + 1 < NSTEP) MFMAS(avB, s2 + 1)
    }

    if (!HEAD) {
        #pragma unroll
        for (int m = 0; m < 4; ++m)
            #pragma unroll
            for (int n = 0; n < 4; ++n) {
                int col = wc * 64 + n * 16 + r16;
                float bvf = bias[col];
                #pragma unroll
                for (int r = 0; r < 4; ++r) {
                    int grow = row0 + wr * 64 + m * 16 + kg * 4 + r;
                    float val = fmaxf(acc[m][n][r] + bvf, 0.0f);
                    outc[((size_t)(8 + wc * 4 + n) * MROWS + grow) * 16 + r16] = f2bf(val);
                }
            }
    } else {
        // stage relu'd h3 tile into LDS (overwrites Bs region; W3 sits above it)
        __syncthreads();
        u16* Hs = (u16*)smem;                              // [320][134]
        short* W3 = (short*)(smem + HS_BYTES);             // [64][136]
        #pragma unroll
        for (int m = 0; m < 4; ++m)
            #pragma unroll
            for (int n = 0; n < 4; ++n) {
                int col = wc * 64 + n * 16 + r16;
                float bvf = bias[col];
                #pragma unroll
                for (int r = 0; r < 4; ++r) {
                    int lrow = wr * 64 + m * 16 + kg * 4 + r;
                    Hs[lrow * 134 + col] = f2bf(fmaxf(acc[m][n][r] + bvf, 0.0f));
                }
            }
        __syncthreads();
        // MFMA head: wave wid -> m-tiles {2*wid, 2*wid+1}; 4 n-tiles (hi0,hi1,lo0,lo1)
        f32x4 hacc[2][4];
        #pragma unroll
        for (int m = 0; m < 2; ++m)
            #pragma unroll
            for (int n = 0; n < 4; ++n)
                hacc[m][n] = (f32x4){0.f, 0.f, 0.f, 0.f};
        #pragma unroll
        for (int ks = 0; ks < 4; ++ks) {
            const int k0 = ks * 32 + kg * 8;
            bf16x8 ha[2], hbv[4];
            #pragma unroll
            for (int m = 0; m < 2; ++m)
                ha[m] = *(const bf16x8*)&Hs[(wid * 32 + m * 16 + r16) * 134 + k0];
            #pragma unroll
            for (int n = 0; n < 4; ++n)
                hbv[n] = *(const bf16x8*)&W3[(n * 16 + r16) * 136 + k0];
            #pragma unroll
            for (int m = 0; m < 2; ++m)
                #pragma unroll
                for (int n = 0; n < 4; ++n)
                    hacc[m][n] = __builtin_amdgcn_mfma_f32_16x16x32_bf16(
                        ha[m], hbv[n], hacc[m][n], 0, 0, 0);
        }
        #pragma unroll
        for (int m = 0; m < 2; ++m)
            #pragma unroll
            for (int nt = 0; nt < 2; ++nt) {
                int col = nt * 16 + r16;
                if (col < 24) {
                    float hbias = hb[col];
                    int tt = col >> 1, cc = col & 1;
                    #pragma unroll
                    for (int r = 0; r < 4; ++r) {
                        int grow = row0 + wid * 32 + m * 16 + kg * 4 + r;
                        float val = hacc[m][nt][r] + hacc[m][nt + 2][r] + hbias;
                        int n = grow >> 3, b = grow & 7;
                        outf[((size_t)(b * TIN + tt) * NNODE + n) * 2 + cc] = val;
                    }
                }
            }
    }
}

// ---------------------------------------------------------------------------
extern "C" void kernel_launch(void* const* d_in, const int* in_sizes, int n_in,
                              void* d_out, int out_size, void* d_ws, size_t ws_size,
                              hipStream_t stream) {
    const float* x      = (const float*)d_in[0];
    const int*   ei     = (const int*)d_in[1];
    const float* Wl0    = (const float*)d_in[2];
    const float* Wr0    = (const float*)d_in[3];
    const float* bl0    = (const float*)d_in[4];
    const float* Wl12   = (const float*)d_in[5];
    const float* Wr12   = (const float*)d_in[6];
    const float* bl12   = (const float*)d_in[7];
    const float* bn_g   = (const float*)d_in[8];
    const float* bn_b   = (const float*)d_in[9];
    const float* bn_m   = (const float*)d_in[10];
    const float* bn_v   = (const float*)d_in[11];
    const float* headW  = (const float*)d_in[12];
    const float* headb  = (const float*)d_in[13];
    float* out = (float*)d_out;

    u16* X0 = (u16*)d_ws;                            // M x 48 row-major (+32 slack)
    u16* X1 = X0 + (size_t)MROWS * 48 + 32;          // [16][M][16] chunked
    u16* X2 = X1 + (size_t)MROWS * 256;              // [16][M][16] chunked
    u16* W0T = X2 + (size_t)MROWS * 256;             // 128 x 64 (rows 48..63 zero)
    u16* W1T = W0T + 128 * 64;                       // 128 x 256
    u16* W2T = W1T + 128 * 256;                      // 128 x 256
    u16* W3T = W2T + 128 * 256;                      // 64 x 128 (hi | lo)
    float* bias012 = (float*)(W3T + 64 * 128);       // 3 x 128
    float* inv_deg = bias012 + 3 * 128;              // N
    int* degi    = (int*)(inv_deg + NNODE);          // N
    int* row_ptr = degi + NNODE;                     // N+1
    int* cursor  = row_ptr + (NNODE + 1);            // N
    int* csr_src = cursor + NNODE;                   // E

    hipMemsetAsync(degi, 0, sizeof(int) * NNODE, stream);

    fused_pre<<<1066, 256, 0, stream>>>(x, X0, ei, degi, Wl0, Wr0, bl0, Wl12, Wr12,
                                        bl12, bn_g, bn_b, bn_m, bn_v, headW,
                                        W0T, W1T, W2T, W3T, bias012);
    scan_kernel<<<1, 1024, 0, stream>>>(degi, row_ptr, inv_deg, cursor);
    csr_fill<<<(NEDGE + 255) / 256, 256, 0, stream>>>(ei, row_ptr, cursor, csr_src);

    // layer 0
    agg24<<<NNODE / 2, 192, 0, stream>>>(X0, row_ptr, csr_src, inv_deg);
    gemm_mfma<64, 48, false, false><<<250, 640, 0, stream>>>(X0, W0T, bias012,
                                                             nullptr, nullptr, X1, nullptr);
    // layer 1
    agg128c<<<(NNODE / 2) * 8, 128, 0, stream>>>(X1, row_ptr, csr_src, inv_deg);
    gemm_mfma<256, 0, true, false><<<250, 640, 0, stream>>>(X1, W1T, bias012 + 128,
                                                            nullptr, nullptr, X2, nullptr);
    // layer 2 + fused MFMA head
    agg128c<<<(NNODE / 2) * 8, 128, 0, stream>>>(X2, row_ptr, csr_src, inv_deg);
    gemm_mfma<256, 0, true, true><<<250, 640, 0, stream>>>(X2, W2T, bias012 + 256,
                                                           W3T, headb, nullptr, out);
}

// Round 13
// 248.052 us; speedup vs baseline: 1.0829x; 1.0829x over previous
//
#include <hip/hip_runtime.h>

#define NB 8
#define NNODE 10000
#define NEDGE 160000
#define MROWS 80000
#define TIN 12
#define EPSBN 1e-5f

typedef __attribute__((ext_vector_type(8))) short bf16x8;
typedef __attribute__((ext_vector_type(4))) float f32x4;
typedef unsigned short u16;
typedef unsigned int u32;

static __device__ __forceinline__ u16 f2bf(float f) {
    unsigned int u = __builtin_bit_cast(unsigned int, f);
    u = (u + 0x7fffu + ((u >> 16) & 1u)) >> 16;
    return (u16)u;
}
static __device__ __forceinline__ float bf2f(u16 h) {
    unsigned int u = ((unsigned int)h) << 16;
    return __builtin_bit_cast(float, u);
}

// ---------------------------------------------------------------------------
__global__ void deg_kernel(const int* __restrict__ ei, int* __restrict__ degi) {
    int e = blockIdx.x * blockDim.x + threadIdx.x;
    if (e < NEDGE) atomicAdd(&degi[ei[NEDGE + e]], 1);
}

// prefix scan over deg -> row_ptr, inv_deg; also zeroes cursor
__global__ __launch_bounds__(1024) void scan_kernel(const int* __restrict__ degi,
                                                    int* __restrict__ row_ptr,
                                                    float* __restrict__ inv_deg,
                                                    int* __restrict__ cursor) {
    __shared__ int sdata[1024];
    const int t = threadIdx.x;
    const int CH = 10;
    const int i0 = t * CH;
    int sum = 0;
    for (int i = i0; i < i0 + CH && i < NNODE; ++i) sum += degi[i];
    sdata[t] = sum;
    for (int off = 1; off < 1024; off <<= 1) {
        __syncthreads();
        int vv = (t >= off) ? sdata[t - off] : 0;
        __syncthreads();
        sdata[t] += vv;
    }
    __syncthreads();
    int run = sdata[t] - sum;
    for (int i = i0; i < i0 + CH && i < NNODE; ++i) {
        row_ptr[i] = run;
        int d = degi[i];
        run += d;
        inv_deg[i] = 1.0f / (float)max(d, 1);
        cursor[i] = 0;
    }
    if (t == 1023) row_ptr[NNODE] = sdata[1023];
}

// fused stage 2: [0,313) transpose_x | [313,441) prep | [441,1066) csr_fill
__global__ __launch_bounds__(256) void fused2(const float* __restrict__ x,
                                              u16* __restrict__ X0,
                                              const int* __restrict__ ei,
                                              const int* __restrict__ row_ptr,
                                              int* __restrict__ cursor,
                                              int* __restrict__ csr_src,
                                              const float* __restrict__ Wl0,
                                              const float* __restrict__ Wr0,
                                              const float* __restrict__ bl0,
                                              const float* __restrict__ Wl12,
                                              const float* __restrict__ Wr12,
                                              const float* __restrict__ bl12,
                                              const float* __restrict__ g,
                                              const float* __restrict__ bb,
                                              const float* __restrict__ m,
                                              const float* __restrict__ v,
                                              const float* __restrict__ hW,
                                              u16* __restrict__ W0T, u16* __restrict__ W1T,
                                              u16* __restrict__ W2T, u16* __restrict__ W3T,
                                              float* __restrict__ bias012) {
    int blk = blockIdx.x;
    if (blk < 313) {
        int row = blk * 256 + threadIdx.x;        // row = n*8 + b
        if (row >= MROWS) return;
        int n = row >> 3, b = row & 7;
        u32 w[12];
        #pragma unroll
        for (int tt = 0; tt < 12; ++tt) {
            float2 vv = *(const float2*)&x[(size_t)((b * 12 + tt) * NNODE + n) * 2];
            w[tt] = (u32)f2bf(vv.x) | ((u32)f2bf(vv.y) << 16);
        }
        u32* dst = (u32*)&X0[(size_t)row * 48 + 24];
        *(uint4*)(dst + 0) = make_uint4(w[0], w[1], w[2], w[3]);
        *(uint4*)(dst + 4) = make_uint4(w[4], w[5], w[6], w[7]);
        *(uint4*)(dst + 8) = make_uint4(w[8], w[9], w[10], w[11]);
    } else if (blk < 441) {
        int c = blk - 313, k = threadIdx.x;
        float s0 = g[c] / sqrtf(v[c] + EPSBN);
        float s1 = g[128 + c] / sqrtf(v[128 + c] + EPSBN);
        float s2 = g[256 + c] / sqrtf(v[256 + c] + EPSBN);
        if (k < 64) {
            float val = (k < 24) ? Wl0[k * 128 + c] : ((k < 48) ? Wr0[(k - 24) * 128 + c] : 0.0f);
            W0T[c * 64 + k] = f2bf(val * s0);
        }
        float v1 = (k < 128) ? Wl12[k * 128 + c] : Wr12[(k - 128) * 128 + c];
        W1T[c * 256 + k] = f2bf(v1 * s1);
        float v2 = (k < 128) ? Wl12[128 * 128 + k * 128 + c]
                             : Wr12[128 * 128 + (k - 128) * 128 + c];
        W2T[c * 256 + k] = f2bf(v2 * s2);
        if (k < 128 && c < 64) {
            // head weights, hi/lo bf16 split: rows 0..31 hi, 32..63 lo
            int cc = c & 31;
            float w3 = (cc < 24) ? hW[k * 24 + cc] : 0.0f;
            u16 hi = f2bf(w3);
            if (c < 32) W3T[c * 128 + k] = hi;
            else        W3T[c * 128 + k] = f2bf(w3 - bf2f(hi));
        }
        if (k < 3) {
            float sl = g[k * 128 + c] / sqrtf(v[k * 128 + c] + EPSBN);
            float blv = (k == 0) ? bl0[c] : bl12[(k - 1) * 128 + c];
            bias012[k * 128 + c] = blv * sl + bb[k * 128 + c] - m[k * 128 + c] * sl;
        }
    } else {
        int e = (blk - 441) * 256 + threadIdx.x;
        if (e < NEDGE) {
            int d = ei[NEDGE + e];
            int pos = atomicAdd(&cursor[d], 1);
            csr_src[row_ptr[d] + pos] = ei[e];
        }
    }
}

// mean-aggregation K=24 on row-major X0 (stride 48), 2 nodes/block, unroll-4
__global__ __launch_bounds__(192) void agg24(u16* __restrict__ X0,
                                             const int* __restrict__ rp,
                                             const int* __restrict__ cs,
                                             const float* __restrict__ inv) {
    int u = threadIdx.x;
    int n = blockIdx.x * 2 + (u / 96);
    int w = u % 96;
    int b = w / 12, cp = w % 12;
    int p0 = rp[n], p1 = rp[n + 1];
    float a0 = 0, a1 = 0, b0 = 0, b1 = 0, c0 = 0, c1 = 0, d0 = 0, d1 = 0;
    int p = p0;
    for (; p + 4 <= p1; p += 4) {
        int s0 = cs[p], s1 = cs[p + 1], s2 = cs[p + 2], s3 = cs[p + 3];
        u32 v0 = *(const u32*)&X0[(s0 * NB + b) * 48 + 24 + cp * 2];
        u32 v1 = *(const u32*)&X0[(s1 * NB + b) * 48 + 24 + cp * 2];
        u32 v2 = *(const u32*)&X0[(s2 * NB + b) * 48 + 24 + cp * 2];
        u32 v3 = *(const u32*)&X0[(s3 * NB + b) * 48 + 24 + cp * 2];
        a0 += bf2f((u16)(v0 & 0xffff)); a1 += bf2f((u16)(v0 >> 16));
        b0 += bf2f((u16)(v1 & 0xffff)); b1 += bf2f((u16)(v1 >> 16));
        c0 += bf2f((u16)(v2 & 0xffff)); c1 += bf2f((u16)(v2 >> 16));
        d0 += bf2f((u16)(v3 & 0xffff)); d1 += bf2f((u16)(v3 >> 16));
    }
    for (; p < p1; ++p) {
        int s = cs[p];
        u32 vv = *(const u32*)&X0[(s * NB + b) * 48 + 24 + cp * 2];
        a0 += bf2f((u16)(vv & 0xffff)); a1 += bf2f((u16)(vv >> 16));
    }
    float sc = inv[n];
    float r0 = (a0 + b0) + (c0 + d0), r1 = (a1 + b1) + (c1 + d1);
    u32 o = (u32)f2bf(r0 * sc) | ((u32)f2bf(r1 * sc) << 16);
    *(u32*)&X0[(n * NB + b) * 48 + cp * 2] = o;
}

// chunked mean-aggregation K=128 (r8 best-measured): X layout [16][MROWS][16],
// h in chunks 8..15, mean -> 0..7. chunk = blockIdx&7 (XCD-pinned).
// neighbor list staged in LDS, then 8-deep independent gather unroll.
#define GLD(s) (*(const u32*)&hb[((s) * NB + b) * 16 + q * 2])
__global__ __launch_bounds__(64) void agg128c(u16* __restrict__ X,
                                              const int* __restrict__ rp,
                                              const int* __restrict__ cs,
                                              const float* __restrict__ inv) {
    __shared__ int slist[128];
    int bid = blockIdx.x;
    int c = bid & 7;
    int n = bid >> 3;
    int t = threadIdx.x;
    int b = t >> 3, q = t & 7;
    int p0 = rp[n], p1 = rp[n + 1];
    const u16* hb = X + ((size_t)(8 + c) * MROWS) * 16;
    float a0 = 0, a1 = 0, b0 = 0, b1 = 0, c0 = 0, c1 = 0, d0 = 0, d1 = 0;
    float e0 = 0, e1 = 0, f0 = 0, f1 = 0, g0 = 0, g1 = 0, h0 = 0, h1 = 0;
    for (int base = p0; base < p1; base += 128) {
        int cnt = p1 - base;
        if (cnt > 128) cnt = 128;
        __syncthreads();
        for (int i = t; i < cnt; i += 64) slist[i] = cs[base + i];
        __syncthreads();
        int i = 0;
        for (; i + 8 <= cnt; i += 8) {
            int s0 = slist[i + 0], s1 = slist[i + 1], s2 = slist[i + 2], s3 = slist[i + 3];
            int s4 = slist[i + 4], s5 = slist[i + 5], s6 = slist[i + 6], s7 = slist[i + 7];
            u32 v0 = GLD(s0), v1 = GLD(s1), v2 = GLD(s2), v3 = GLD(s3);
            u32 v4 = GLD(s4), v5 = GLD(s5), v6 = GLD(s6), v7 = GLD(s7);
            a0 += bf2f((u16)(v0 & 0xffff)); a1 += bf2f((u16)(v0 >> 16));
            b0 += bf2f((u16)(v1 & 0xffff)); b1 += bf2f((u16)(v1 >> 16));
            c0 += bf2f((u16)(v2 & 0xffff)); c1 += bf2f((u16)(v2 >> 16));
            d0 += bf2f((u16)(v3 & 0xffff)); d1 += bf2f((u16)(v3 >> 16));
            e0 += bf2f((u16)(v4 & 0xffff)); e1 += bf2f((u16)(v4 >> 16));
            f0 += bf2f((u16)(v5 & 0xffff)); f1 += bf2f((u16)(v5 >> 16));
            g0 += bf2f((u16)(v6 & 0xffff)); g1 += bf2f((u16)(v6 >> 16));
            h0 += bf2f((u16)(v7 & 0xffff)); h1 += bf2f((u16)(v7 >> 16));
        }
        for (; i < cnt; ++i) {
            int s = slist[i];
            u32 vv = GLD(s);
            a0 += bf2f((u16)(vv & 0xffff)); a1 += bf2f((u16)(vv >> 16));
        }
    }
    float sc = inv[n];
    float r0 = ((a0 + b0) + (c0 + d0)) + ((e0 + f0) + (g0 + h0));
    float r1 = ((a1 + b1) + (c1 + d1)) + ((e1 + f1) + (g1 + h1));
    u32 o = (u32)f2bf(r0 * sc) | ((u32)f2bf(r1 * sc) << 16);
    *(u32*)&X[((size_t)c * MROWS + n * NB + b) * 16 + q * 2] = o;
}

// MFMA GEMM (r8 config, measured best): M-tile 320 x N 128, 10 waves, grid 250,
// W in LDS slab (conflict-free), A direct global->VGPR depth-1 prefetch.
// HEAD: fused MFMA 128->24 head.
#define LOADA(dst, stp) { \
    const int k0_ = (stp) * 32 + kg * 8; \
    _Pragma("unroll") \
    for (int m_ = 0; m_ < 4; ++m_) { \
        const int row_ = rowbase + m_ * 16; \
        const u16* ap_; \
        if (INC) ap_ = A + ((size_t)(k0_ >> 4) * MROWS + row_) * 16 + (k0_ & 15); \
        else     ap_ = A + (size_t)row_ * LDA + k0_; \
        dst[m_] = *(const bf16x8*)ap_; \
    } }

#define MFMAS(av, stp) { \
    const int k0_ = (stp) * 32 + kg * 8; \
    bf16x8 bv_[4]; \
    _Pragma("unroll") \
    for (int n_ = 0; n_ < 4; ++n_) \
        bv_[n_] = *(const bf16x8*)&BsF[(((k0_) >> 3) * 128 + (wc * 64 + n_ * 16 + r16)) * 8]; \
    _Pragma("unroll") \
    for (int m_ = 0; m_ < 4; ++m_) \
        _Pragma("unroll") \
        for (int n_ = 0; n_ < 4; ++n_) \
            acc[m_][n_] = __builtin_amdgcn_mfma_f32_16x16x32_bf16(av[m_], bv_[n_], acc[m_][n_], 0, 0, 0); }

template<int K, int LDA, bool INC, bool HEAD>
__global__ __launch_bounds__(640) void gemm_mfma(const u16* __restrict__ A,
                                                 const u16* __restrict__ WT,
                                                 const float* __restrict__ bias,
                                                 const u16* __restrict__ W3Tg,
                                                 const float* __restrict__ hb,
                                                 u16* __restrict__ outc,
                                                 float* __restrict__ outf) {
    constexpr int NSTEP = K / 32;
    constexpr int BS_BYTES = K * 128 * 2;                  // slab [K/8][128][8]
    constexpr int HS_BYTES = 320 * 134 * 2;                // 85760
    constexpr int W3_BYTES = 64 * 136 * 2;                 // 17408
    constexpr int HEAD_BYTES = HS_BYTES + W3_BYTES;        // 103168 >= BS_BYTES
    constexpr int SMEM_BYTES = HEAD ? (BS_BYTES > HEAD_BYTES ? BS_BYTES : HEAD_BYTES)
                                    : BS_BYTES;
    __shared__ __align__(16) char smem[SMEM_BYTES];
    short* BsF = (short*)smem;

    const int t = threadIdx.x;
    const int row0 = blockIdx.x * 320;
    const int lane = t & 63, wid = t >> 6;
    const int wr = wid >> 1, wc = wid & 1;
    const int r16 = lane & 15, kg = lane >> 4;

    if (t < 512) {
        const int col = t >> 2, q = t & 3;
        #pragma unroll
        for (int j = 0; j < K / 32; ++j) {
            int k0 = q * (K / 4) + j * 8;
            *(bf16x8*)&BsF[((k0 >> 3) * 128 + col) * 8] =
                *(const bf16x8*)&WT[col * K + k0];
        }
    }
    if (HEAD) {
        short* W3 = (short*)(smem + HS_BYTES);             // [64][136]
        for (int i = t; i < 1024; i += 640) {
            int row = i >> 4, j = i & 15;
            *(bf16x8*)&W3[row * 136 + j * 8] = *(const bf16x8*)&W3Tg[row * 128 + j * 8];
        }
    }
    __syncthreads();

    f32x4 acc[4][4];
    #pragma unroll
    for (int m = 0; m < 4; ++m)
        #pragma unroll
        for (int n = 0; n < 4; ++n)
            acc[m][n] = (f32x4){0.f, 0.f, 0.f, 0.f};

    const int rowbase = row0 + wr * 64 + r16;

    bf16x8 avA[4], avB[4];
    LOADA(avA, 0)
    #pragma unroll
    for (int s2 = 0; s2 < NSTEP; s2 += 2) {
        if (s2 + 1 < NSTEP) LOADA(avB, s2 + 1)
        MFMAS(avA, s2)
        if (s2 + 2 < NSTEP) LOADA(avA, s2 + 2)
        if (s2 + 1 < NSTEP) MFMAS(avB, s2 + 1)
    }

    if (!HEAD) {
        #pragma unroll
        for (int m = 0; m < 4; ++m)
            #pragma unroll
            for (int n = 0; n < 4; ++n) {
                int col = wc * 64 + n * 16 + r16;
                float bvf = bias[col];
                #pragma unroll
                for (int r = 0; r < 4; ++r) {
                    int grow = row0 + wr * 64 + m * 16 + kg * 4 + r;
                    float val = fmaxf(acc[m][n][r] + bvf, 0.0f);
                    outc[((size_t)(8 + wc * 4 + n) * MROWS + grow) * 16 + r16] = f2bf(val);
                }
            }
    } else {
        // stage relu'd h3 tile into LDS (overwrites Bs region; W3 sits above it)
        __syncthreads();
        u16* Hs = (u16*)smem;                              // [320][134]
        short* W3 = (short*)(smem + HS_BYTES);             // [64][136]
        #pragma unroll
        for (int m = 0; m < 4; ++m)
            #pragma unroll
            for (int n = 0; n < 4; ++n) {
                int col = wc * 64 + n * 16 + r16;
                float bvf = bias[col];
                #pragma unroll
                for (int r = 0; r < 4; ++r) {
                    int lrow = wr * 64 + m * 16 + kg * 4 + r;
                    Hs[lrow * 134 + col] = f2bf(fmaxf(acc[m][n][r] + bvf, 0.0f));
                }
            }
        __syncthreads();
        // MFMA head: wave wid -> m-tiles {2*wid, 2*wid+1}; 4 n-tiles (hi0,hi1,lo0,lo1)
        f32x4 hacc[2][4];
        #pragma unroll
        for (int m = 0; m < 2; ++m)
            #pragma unroll
            for (int n = 0; n < 4; ++n)
                hacc[m][n] = (f32x4){0.f, 0.f, 0.f, 0.f};
        #pragma unroll
        for (int ks = 0; ks < 4; ++ks) {
            const int k0 = ks * 32 + kg * 8;
            bf16x8 ha[2], hbv[4];
            #pragma unroll
            for (int m = 0; m < 2; ++m)
                ha[m] = *(const bf16x8*)&Hs[(wid * 32 + m * 16 + r16) * 134 + k0];
            #pragma unroll
            for (int n = 0; n < 4; ++n)
                hbv[n] = *(const bf16x8*)&W3[(n * 16 + r16) * 136 + k0];
            #pragma unroll
            for (int m = 0; m < 2; ++m)
                #pragma unroll
                for (int n = 0; n < 4; ++n)
                    hacc[m][n] = __builtin_amdgcn_mfma_f32_16x16x32_bf16(
                        ha[m], hbv[n], hacc[m][n], 0, 0, 0);
        }
        #pragma unroll
        for (int m = 0; m < 2; ++m)
            #pragma unroll
            for (int nt = 0; nt < 2; ++nt) {
                int col = nt * 16 + r16;
                if (col < 24) {
                    float hbias = hb[col];
                    int tt = col >> 1, cc = col & 1;
                    #pragma unroll
                    for (int r = 0; r < 4; ++r) {
                        int grow = row0 + wid * 32 + m * 16 + kg * 4 + r;
                        float val = hacc[m][nt][r] + hacc[m][nt + 2][r] + hbias;
                        int n = grow >> 3, b = grow & 7;
                        outf[((size_t)(b * TIN + tt) * NNODE + n) * 2 + cc] = val;
                    }
                }
            }
    }
}

// ---------------------------------------------------------------------------
extern "C" void kernel_launch(void* const* d_in, const int* in_sizes, int n_in,
                              void* d_out, int out_size, void* d_ws, size_t ws_size,
                              hipStream_t stream) {
    const float* x      = (const float*)d_in[0];
    const int*   ei     = (const int*)d_in[1];
    const float* Wl0    = (const float*)d_in[2];
    const float* Wr0    = (const float*)d_in[3];
    const float* bl0    = (const float*)d_in[4];
    const float* Wl12   = (const float*)d_in[5];
    const float* Wr12   = (const float*)d_in[6];
    const float* bl12   = (const float*)d_in[7];
    const float* bn_g   = (const float*)d_in[8];
    const float* bn_b   = (const float*)d_in[9];
    const float* bn_m   = (const float*)d_in[10];
    const float* bn_v   = (const float*)d_in[11];
    const float* headW  = (const float*)d_in[12];
    const float* headb  = (const float*)d_in[13];
    float* out = (float*)d_out;

    u16* X0 = (u16*)d_ws;                            // M x 48 row-major (+32 slack)
    u16* X1 = X0 + (size_t)MROWS * 48 + 32;          // [16][M][16] chunked
    u16* X2 = X1 + (size_t)MROWS * 256;              // [16][M][16] chunked
    u16* W0T = X2 + (size_t)MROWS * 256;             // 128 x 64 (rows 48..63 zero)
    u16* W1T = W0T + 128 * 64;                       // 128 x 256
    u16* W2T = W1T + 128 * 256;                      // 128 x 256
    u16* W3T = W2T + 128 * 256;                      // 64 x 128 (hi | lo)
    float* bias012 = (float*)(W3T + 64 * 128);       // 3 x 128
    float* inv_deg = bias012 + 3 * 128;              // N
    int* degi    = (int*)(inv_deg + NNODE);          // N
    int* row_ptr = degi + NNODE;                     // N+1
    int* cursor  = row_ptr + (NNODE + 1);            // N
    int* csr_src = cursor + NNODE;                   // E

    hipMemsetAsync(degi, 0, sizeof(int) * NNODE, stream);

    deg_kernel<<<(NEDGE + 255) / 256, 256, 0, stream>>>(ei, degi);
    scan_kernel<<<1, 1024, 0, stream>>>(degi, row_ptr, inv_deg, cursor);
    fused2<<<1066, 256, 0, stream>>>(x, X0, ei, row_ptr, cursor, csr_src,
                                     Wl0, Wr0, bl0, Wl12, Wr12, bl12,
                                     bn_g, bn_b, bn_m, bn_v, headW,
                                     W0T, W1T, W2T, W3T, bias012);

    // layer 0
    agg24<<<NNODE / 2, 192, 0, stream>>>(X0, row_ptr, csr_src, inv_deg);
    gemm_mfma<64, 48, false, false><<<250, 640, 0, stream>>>(X0, W0T, bias012,
                                                             nullptr, nullptr, X1, nullptr);
    // layer 1
    agg128c<<<NNODE * 8, 64, 0, stream>>>(X1, row_ptr, csr_src, inv_deg);
    gemm_mfma<256, 0, true, false><<<250, 640, 0, stream>>>(X1, W1T, bias012 + 128,
                                                            nullptr, nullptr, X2, nullptr);
    // layer 2 + fused MFMA head
    agg128c<<<NNODE * 8, 64, 0, stream>>>(X2, row_ptr, csr_src, inv_deg);
    gemm_mfma<256, 0, true, true><<<250, 640, 0, stream>>>(X2, W2T, bias012 + 256,
                                                           W3T, headb, nullptr, out);
}